// Round 5
// baseline (309.011 us; speedup 1.0000x reference)
//
#include <hip/hip_runtime.h>
#include <cstdint>

typedef float floatx4 __attribute__((ext_vector_type(4)));
typedef _Float16 half8 __attribute__((ext_vector_type(8)));
typedef _Float16 half4v __attribute__((ext_vector_type(4)));

#define D_DIM 256
#define HW 1024
#define K_CODES 1024
#define NPIX 32768          // B*H*W
#define NELEM 8388608       // B*D*H*W

// output layout (floats): [quantized 8388608][q_loss][e_loss][vq_loss][idx 32768]
#define OFF_QLOSS 8388608
#define OFF_ELOSS 8388609
#define OFF_VQ    8388610
#define OFF_IDX   8388611

// ws layout (bytes) — total ~0.94 MB (< 1.18 MB proven in round 1)
#define WS_IDX     0         // int * 32768 = 131072
#define WS_C2      131072    // float * 1024 = 4096
#define WS_C2P     135168    // float * 1024 = 4096 (c2 + 1.0, for positive packed scores)
#define WS_CNT     139264    // int (+pad) = 64
#define WS_PART    139328    // double * 512 = 4096
#define WS_FLAGPX  143424    // int * 8192 = 32768
#define WS_FLAGTOP 176192    // floatx4 * 2 * 8192 = 262144
#define WS_CBS     438336    // swizzled fp16 codebook = 524288
#define FLAG_CAP   8192

// flag margin: ref fp32 window 6.1e-5 + fp16 GEMM err ~6e-5 + 2x packing quant 2.4e-4
#define MARGIN 5.0e-4f

// ---- numpy pairwise sum emulation for sum(v*v) over 256 elements ----
__device__ __forceinline__ float np_pairwise_sq_256(const float* __restrict__ a, int stride) {
    float half[2];
#pragma unroll
    for (int h = 0; h < 2; ++h) {
        const float* p = a + (size_t)(h * 128) * stride;
        float r[8];
#pragma unroll
        for (int j = 0; j < 8; ++j) { float t = p[(size_t)j * stride]; r[j] = __fmul_rn(t, t); }
        for (int i = 8; i < 128; i += 8)
#pragma unroll
            for (int j = 0; j < 8; ++j) {
                float t = p[(size_t)(i + j) * stride];
                r[j] = __fadd_rn(r[j], __fmul_rn(t, t));
            }
        half[h] = __fadd_rn(__fadd_rn(__fadd_rn(r[0], r[1]), __fadd_rn(r[2], r[3])),
                            __fadd_rn(__fadd_rn(r[4], r[5]), __fadd_rn(r[6], r[7])));
    }
    return __fadd_rn(half[0], half[1]);
}

// ---------------- kernel 0: prep ----------------
// blocks 0..255: swizzle codebook into MFMA-fragment order (scaled x1024):
//   half index = (((quarter*16 + ch)*8 + s)*64 + (q*16 + l15))*8 + j
//   where code c: quarter=c>>8, ch=(c>>4)&15, l15=c&15; d: s=d>>5, q=(d>>3)&3, j=d&7.
// blocks 256..259: c2 (numpy-pairwise exact) + c2p = c2+1; b==256,t==0 zeroes cnt.
__global__ __launch_bounds__(256) void prep_kernel(const float* __restrict__ cb,
                                                   _Float16* __restrict__ cbs,
                                                   float* __restrict__ c2,
                                                   float* __restrict__ c2p,
                                                   int* __restrict__ cnt) {
    int b = blockIdx.x;
    if (b < 256) {
        int idx = b * 256 + threadIdx.x;   // (code, d-quad)
        int c = idx >> 6;
        int d = (idx & 63) * 4;
        int s = d >> 5, q = (d >> 3) & 3, j0 = d & 7;
        int quarter = c >> 8, ch = (c >> 4) & 15, l15 = c & 15;
        int lane = q * 16 + l15;
        size_t o = ((((size_t)(quarter * 16 + ch) * 8 + s) * 64 + lane) * 8 + j0);
        floatx4 v = *(const floatx4*)(cb + (size_t)c * D_DIM + d);
        half4v h;
#pragma unroll
        for (int j = 0; j < 4; ++j) h[j] = (_Float16)(v[j] * 1024.0f);  // exact pow2
        *(half4v*)(cbs + o) = h;
    } else {
        if (b == 256 && threadIdx.x == 0) *cnt = 0;
        int k = (b - 256) * 256 + threadIdx.x;
        float v = np_pairwise_sq_256(cb + (size_t)k * D_DIM, 1);
        c2[k] = v;
        c2p[k] = __fadd_rn(v, 1.0f);
    }
}

// packed top-4 insert (u32: high bits = biased score, low 10 = code)
__device__ __forceinline__ void ins4p(unsigned v, unsigned* S) {
    if (v < S[3]) {
        S[3] = v;
#pragma unroll
        for (int j = 3; j > 0; --j)
            if (S[j] < S[j - 1]) { unsigned tmp = S[j]; S[j] = S[j - 1]; S[j - 1] = tmp; }
    }
}

// ---------------- kernel 1: swizzled-stream MFMA GEMM + packed top-2/4 ----------------
// Block = 32 px; 4 waves = 4 code-quarters (256 codes each). B loads are fully
// contiguous (lane*16B) thanks to prep's fragment-order codebook. No LDS in loop.
__global__ __launch_bounds__(256, 3) void gemm_swz(
        const float* __restrict__ x, const _Float16* __restrict__ cbs,
        const float* __restrict__ c2p, float* __restrict__ out_idx,
        int* __restrict__ idxbuf, int* __restrict__ cnt,
        int* __restrict__ flagPx, floatx4* __restrict__ flagTop) {
    __shared__ uint2 scr[32][65];   // [px][64 partials + pad] packed (m1,m2)

    const int t = threadIdx.x;
    const int w = t >> 6;        // wave = code quarter
    const int l = t & 63;
    const int l15 = l & 15;
    const int q = l >> 4;
    const int px0 = blockIdx.x * 32;
    const int bimg = px0 >> 10;
    const int hwb = px0 & 1023;
    const float* xb = x + (size_t)bimg * (D_DIM * HW) + hwb;

    // ---- A frags: 32 px x 256 d; A[m=l15][k=q*8+j], px = r*16+l15, d = s*32+q*8+j
    half8 A[2][8];
#pragma unroll
    for (int r = 0; r < 2; ++r)
#pragma unroll
        for (int s = 0; s < 8; ++s) {
            float tmp[8];
#pragma unroll
            for (int j = 0; j < 8; ++j)
                tmp[j] = xb[(size_t)(s * 32 + q * 8 + j) * HW + r * 16 + l15];
            half8 h;
#pragma unroll
            for (int j = 0; j < 8; ++j) h[j] = (_Float16)tmp[j];
            A[r][s] = h;
        }

    // ---- stream this quarter's codes from the fragment-ordered buffer ----
    const _Float16* base = cbs + (size_t)w * 65536;   // quarter block: 16*8*64*8 halves
    half8 B[2][8];
#pragma unroll
    for (int s = 0; s < 8; ++s)
        B[0][s] = *(const half8*)(base + (size_t)s * 512 + l * 8);
    float c2c = c2p[w * 256 + l15];

    unsigned m1[2][4], m2[2][4];
#pragma unroll
    for (int r = 0; r < 2; ++r)
#pragma unroll
        for (int a = 0; a < 4; ++a) { m1[r][a] = 0xFFFFFFFFu; m2[r][a] = 0xFFFFFFFFu; }

#pragma unroll 2
    for (int ch = 0; ch < 16; ++ch) {
        const int cur = ch & 1, nxt = cur ^ 1;
        float c2n = 0.f;
        if (ch < 15) {
            const _Float16* nb = base + (size_t)(ch + 1) * 4096;   // 8*512 halves
#pragma unroll
            for (int s = 0; s < 8; ++s)
                B[nxt][s] = *(const half8*)(nb + (size_t)s * 512 + l * 8);
            c2n = c2p[w * 256 + (ch + 1) * 16 + l15];
        }
        floatx4 acc[2];
        acc[0] = floatx4{0.f, 0.f, 0.f, 0.f};
        acc[1] = floatx4{0.f, 0.f, 0.f, 0.f};
#pragma unroll
        for (int s = 0; s < 8; ++s) {
            acc[0] = __builtin_amdgcn_mfma_f32_16x16x32_f16(A[0][s], B[cur][s], acc[0], 0, 0, 0);
            acc[1] = __builtin_amdgcn_mfma_f32_16x16x32_f16(A[1][s], B[cur][s], acc[1], 0, 0, 0);
        }
        const unsigned code = (unsigned)(w * 256 + ch * 16 + l15);
#pragma unroll
        for (int r = 0; r < 2; ++r)
#pragma unroll
            for (int a = 0; a < 4; ++a) {
                // biased score (1+c2) - 2*dot; cb scaled 2^10 -> coeff 2^-9
                float sb = fmaf(-0.001953125f, acc[r][a], c2c);
                unsigned p = (__float_as_uint(sb) & 0xFFFFFC00u) | code;
                m2[r][a] = min(m2[r][a], max(m1[r][a], p));
                m1[r][a] = min(m1[r][a], p);
            }
        c2c = c2n;
    }

    // ---- merge 64 packed partial top-2s per pixel ----
#pragma unroll
    for (int r = 0; r < 2; ++r)
#pragma unroll
        for (int a = 0; a < 4; ++a) {
            int px = r * 16 + q * 4 + a;          // D row = q*4+reg
            scr[px][w * 16 + l15] = uint2{m1[r][a], m2[r][a]};
        }
    __syncthreads();
    if (t < 32) {
        unsigned S[4] = {0xFFFFFFFFu, 0xFFFFFFFFu, 0xFFFFFFFFu, 0xFFFFFFFFu};
        for (int p = 0; p < 64; ++p) {
            uint2 e = scr[t][p];
            ins4p(e.x, S);
            ins4p(e.y, S);
        }
        int P = px0 + t;
        int best = (int)(S[0] & 1023u);
        idxbuf[P] = best;
        out_idx[P] = (float)best;
        float cs0 = __uint_as_float(S[0] & 0xFFFFFC00u);
        float cs1 = __uint_as_float(S[1] & 0xFFFFFC00u);
        if (cs1 - cs0 <= MARGIN) {
            int pos = atomicAdd(cnt, 1);
            if (pos < FLAG_CAP) {
                float cs2 = __uint_as_float(S[2] & 0xFFFFFC00u);
                float cs3 = __uint_as_float(S[3] & 0xFFFFFC00u);
                flagPx[pos] = P;
                flagTop[2 * pos]     = floatx4{cs0, (float)(S[0] & 1023u), cs1, (float)(S[1] & 1023u)};
                flagTop[2 * pos + 1] = floatx4{cs2, (float)(S[2] & 1023u), cs3, (float)(S[3] & 1023u)};
            }
        }
    }
}

// ---------------- kernel 2: wave-per-flagged-pixel reference-fp32 emulation --------
// ref (numpy fp32): d2_k = fl(fl(x2 - fl(2*mm_k)) + c2_k); argmin, first-index ties.
__global__ __launch_bounds__(256) void rescore_wave(
        const float* __restrict__ x, const float* __restrict__ cb,
        const float* __restrict__ c2, const int* __restrict__ cnt,
        const int* __restrict__ flagPx, const floatx4* __restrict__ flagTop,
        float* __restrict__ out_idx, int* __restrict__ idxbuf) {
    const int wglobal = blockIdx.x * 4 + (threadIdx.x >> 6);
    const int l = threadIdx.x & 63;
    int n = *cnt; if (n > FLAG_CAP) n = FLAG_CAP;
    for (int i = wglobal; i < n; i += 1024) {
        int P = flagPx[i];
        floatx4 ta = flagTop[2 * i], tb = flagTop[2 * i + 1];
        float s1 = ta[0];
        float cs[4] = {ta[0], ta[2], tb[0], tb[2]};
        int   ck[4] = {(int)ta[1], (int)ta[3], (int)tb[1], (int)tb[3]};
        int nc = 1;
        while (nc < 4 && cs[nc] - s1 <= MARGIN) ++nc;

        const float* xcol = x + (size_t)(P >> 10) * D_DIM * HW + (P & 1023);

        // x2 with numpy's exact pairwise order: lanes 0..15 run the 8-acc chains
        float rj = 0.f;
        if (l < 16) {
            int h = l >> 3, j = l & 7;
            const float* p = xcol + (size_t)(h * 128) * HW;
            float v0 = p[(size_t)j * HW];
            rj = __fmul_rn(v0, v0);
            for (int ii = 1; ii < 16; ++ii) {
                float v = p[(size_t)(ii * 8 + j) * HW];
                rj = __fadd_rn(rj, __fmul_rn(v, v));
            }
        }
        float r0 = __shfl(rj, 0), r1 = __shfl(rj, 1), r2 = __shfl(rj, 2), r3 = __shfl(rj, 3);
        float r4 = __shfl(rj, 4), r5 = __shfl(rj, 5), r6 = __shfl(rj, 6), r7 = __shfl(rj, 7);
        float h0 = __fadd_rn(__fadd_rn(__fadd_rn(r0, r1), __fadd_rn(r2, r3)),
                             __fadd_rn(__fadd_rn(r4, r5), __fadd_rn(r6, r7)));
        r0 = __shfl(rj, 8); r1 = __shfl(rj, 9); r2 = __shfl(rj, 10); r3 = __shfl(rj, 11);
        r4 = __shfl(rj, 12); r5 = __shfl(rj, 13); r6 = __shfl(rj, 14); r7 = __shfl(rj, 15);
        float h1 = __fadd_rn(__fadd_rn(__fadd_rn(r0, r1), __fadd_rn(r2, r3)),
                             __fadd_rn(__fadd_rn(r4, r5), __fadd_rn(r6, r7)));
        float x2 = __fadd_rn(h0, h1);

        // f64 dots (stand-in for faithful sgemm): lane covers d = l, l+64, l+128, l+192
        float xv[4];
#pragma unroll
        for (int u = 0; u < 4; ++u) xv[u] = xcol[(size_t)(l + u * 64) * HW];
        double accd[4] = {0.0, 0.0, 0.0, 0.0};
        for (int jc = 0; jc < nc; ++jc) {
            const float* cr = cb + (size_t)ck[jc] * D_DIM;
            double a = 0.0;
#pragma unroll
            for (int u = 0; u < 4; ++u) a += (double)xv[u] * (double)cr[l + u * 64];
#pragma unroll
            for (int off = 32; off > 0; off >>= 1) a += __shfl_down(a, off);
            accd[jc] = a;
        }
        if (l == 0) {
            float bd = INFINITY; int bi = 0x7fffffff;
            for (int jc = 0; jc < nc; ++jc) {
                float mm = (float)accd[jc];
                float t1 = __fsub_rn(x2, __fmul_rn(2.0f, mm));
                float Dq = __fadd_rn(t1, c2[ck[jc]]);
                if (Dq < bd || (Dq == bd && ck[jc] < bi)) { bd = Dq; bi = ck[jc]; }
            }
            idxbuf[P] = bi;
            out_idx[P] = (float)bi;
        }
    }
}

// ---------------- kernel 3: quantized write + loss partials ----------------
// Block = 64 px x 4 d-groups (256 thr). 512 blocks -> 131072 threads.
__global__ __launch_bounds__(256) void quantize_loss_kernel(
        const float* __restrict__ x, const float* __restrict__ cb,
        const int* __restrict__ idxbuf, float* __restrict__ out_q,
        double* __restrict__ partials) {
    const int t = threadIdx.x;
    const int pxl = t & 63;
    const int dg = t >> 6;           // d-group: 64 d each
    const int P = blockIdx.x * 64 + pxl;
    const int bimg = P >> 10, hw = P & 1023;
    const float* xb = x + (size_t)bimg * D_DIM * HW + hw;
    float* qb = out_q + (size_t)bimg * D_DIM * HW + hw;
    const floatx4* crow = (const floatx4*)(cb + (size_t)idxbuf[P] * D_DIM) + dg * 16;
    float lsum = 0.f;
#pragma unroll 4
    for (int i = 0; i < 16; ++i) {
        floatx4 cv = crow[i];
        int dbase = dg * 64 + i * 4;
#pragma unroll
        for (int j = 0; j < 4; ++j) {
            size_t off = (size_t)(dbase + j) * HW;
            float xv = xb[off];
            qb[off] = cv[j];                 // coalesced across pxl lanes
            float df = cv[j] - xv;
            lsum = fmaf(df, df, lsum);
        }
    }
    double ds = (double)lsum;
#pragma unroll
    for (int off = 32; off > 0; off >>= 1) ds += __shfl_down(ds, off);
    __shared__ double sred[4];
    if ((t & 63) == 0) sred[t >> 6] = ds;
    __syncthreads();
    if (t == 0) partials[blockIdx.x] = sred[0] + sred[1] + sred[2] + sred[3];
}

// ---------------- kernel 4: loss scalars ----------------
__global__ __launch_bounds__(64) void finalize_loss(const double* __restrict__ partials,
                                                    float* __restrict__ out) {
    double s = 0.0;
    for (int i = threadIdx.x; i < 512; i += 64) s += partials[i];
#pragma unroll
    for (int off = 32; off > 0; off >>= 1) s += __shfl_down(s, off);
    if (threadIdx.x == 0) {
        double m = s / (double)NELEM;
        out[OFF_QLOSS] = (float)m;
        out[OFF_ELOSS] = (float)m;            // numerically identical to q_loss
        out[OFF_VQ]    = (float)(1.25 * m);   // q + 0.25*e
    }
}

extern "C" void kernel_launch(void* const* d_in, const int* in_sizes, int n_in,
                              void* d_out, int out_size, void* d_ws, size_t ws_size,
                              hipStream_t stream) {
    const float* x  = (const float*)d_in[0];   // (32,256,32,32)
    const float* cb = (const float*)d_in[1];   // (1024,256)
    float* out = (float*)d_out;
    char* ws = (char*)d_ws;

    int*      idxbuf  = (int*)(ws + WS_IDX);
    float*    c2      = (float*)(ws + WS_C2);
    float*    c2p     = (float*)(ws + WS_C2P);
    int*      cnt     = (int*)(ws + WS_CNT);
    double*   partials= (double*)(ws + WS_PART);
    int*      flagPx  = (int*)(ws + WS_FLAGPX);
    floatx4*  flagTop = (floatx4*)(ws + WS_FLAGTOP);
    _Float16* cbs     = (_Float16*)(ws + WS_CBS);

    prep_kernel<<<260, 256, 0, stream>>>(cb, cbs, c2, c2p, cnt);
    gemm_swz<<<NPIX / 32, 256, 0, stream>>>(x, cbs, c2p, out + OFF_IDX, idxbuf,
                                            cnt, flagPx, flagTop);
    rescore_wave<<<256, 256, 0, stream>>>(x, cb, c2, cnt, flagPx, flagTop,
                                          out + OFF_IDX, idxbuf);
    quantize_loss_kernel<<<NPIX / 64, 256, 0, stream>>>(x, cb, idxbuf, out, partials);
    finalize_loss<<<1, 64, 0, stream>>>(partials, out);
}

// Round 6
// 294.175 us; speedup vs baseline: 1.0504x; 1.0504x over previous
//
#include <hip/hip_runtime.h>
#include <cstdint>

typedef float floatx4 __attribute__((ext_vector_type(4)));
typedef _Float16 half8 __attribute__((ext_vector_type(8)));
typedef _Float16 half4v __attribute__((ext_vector_type(4)));

#define D_DIM 256
#define HW 1024
#define K_CODES 1024
#define NPIX 32768          // B*H*W
#define NELEM 8388608       // B*D*H*W

// output layout (floats): [quantized 8388608][q_loss][e_loss][vq_loss][idx 32768]
#define OFF_QLOSS 8388608
#define OFF_ELOSS 8388609
#define OFF_VQ    8388610
#define OFF_IDX   8388611

// ws layout (bytes) — total ~0.94 MB
#define WS_IDX     0         // int * 32768 = 131072
#define WS_C2      131072    // float * 1024 = 4096
#define WS_C2P     135168    // float * 1024 = 4096 (c2 + 1.0, for positive packed scores)
#define WS_CNT     139264    // int (+pad) = 64
#define WS_PART    139328    // double * 512 = 4096
#define WS_FLAGPX  143424    // int * 8192 = 32768
#define WS_FLAGTOP 176192    // floatx4 * 2 * 8192 = 262144
#define WS_CBS     438336    // swizzled fp16 codebook = 524288
#define FLAG_CAP   8192

// flag margin: ref fp32 window 6.1e-5 + fp16 GEMM err ~6e-5 + 2x packing quant 2.4e-4
#define MARGIN 5.0e-4f

// ---- numpy pairwise sum emulation for sum(v*v) over 256 elements ----
__device__ __forceinline__ float np_pairwise_sq_256(const float* __restrict__ a, int stride) {
    float half[2];
#pragma unroll
    for (int h = 0; h < 2; ++h) {
        const float* p = a + (size_t)(h * 128) * stride;
        float r[8];
#pragma unroll
        for (int j = 0; j < 8; ++j) { float t = p[(size_t)j * stride]; r[j] = __fmul_rn(t, t); }
        for (int i = 8; i < 128; i += 8)
#pragma unroll
            for (int j = 0; j < 8; ++j) {
                float t = p[(size_t)(i + j) * stride];
                r[j] = __fadd_rn(r[j], __fmul_rn(t, t));
            }
        half[h] = __fadd_rn(__fadd_rn(__fadd_rn(r[0], r[1]), __fadd_rn(r[2], r[3])),
                            __fadd_rn(__fadd_rn(r[4], r[5]), __fadd_rn(r[6], r[7])));
    }
    return __fadd_rn(half[0], half[1]);
}

// ---------------- kernel 0: prep ----------------
// blocks 0..255: swizzle codebook into MFMA-fragment order (scaled x1024):
//   half index = (((quarter*16 + ch)*8 + s)*64 + (q*16 + l15))*8 + j
//   code c: quarter=c>>8, ch=(c>>4)&15, l15=c&15; d: s=d>>5, q=(d>>3)&3, j=d&7.
// blocks 256..259: c2 (numpy-pairwise exact) + c2p = c2+1; b==256,t==0 zeroes cnt.
__global__ __launch_bounds__(256) void prep_kernel(const float* __restrict__ cb,
                                                   _Float16* __restrict__ cbs,
                                                   float* __restrict__ c2,
                                                   float* __restrict__ c2p,
                                                   int* __restrict__ cnt) {
    int b = blockIdx.x;
    if (b < 256) {
        int idx = b * 256 + threadIdx.x;   // (code, d-quad)
        int c = idx >> 6;
        int d = (idx & 63) * 4;
        int s = d >> 5, q = (d >> 3) & 3, j0 = d & 7;
        int quarter = c >> 8, ch = (c >> 4) & 15, l15 = c & 15;
        int lane = q * 16 + l15;
        size_t o = ((((size_t)(quarter * 16 + ch) * 8 + s) * 64 + lane) * 8 + j0);
        floatx4 v = *(const floatx4*)(cb + (size_t)c * D_DIM + d);
        half4v h;
#pragma unroll
        for (int j = 0; j < 4; ++j) h[j] = (_Float16)(v[j] * 1024.0f);  // exact pow2
        *(half4v*)(cbs + o) = h;
    } else {
        if (b == 256 && threadIdx.x == 0) *cnt = 0;
        int k = (b - 256) * 256 + threadIdx.x;
        float v = np_pairwise_sq_256(cb + (size_t)k * D_DIM, 1);
        c2[k] = v;
        c2p[k] = __fadd_rn(v, 1.0f);
    }
}

// packed top-4 insert (u32: high bits = biased score, low 10 = code)
__device__ __forceinline__ void ins4p(unsigned v, unsigned* S) {
    if (v < S[3]) {
        S[3] = v;
#pragma unroll
        for (int j = 3; j > 0; --j)
            if (S[j] < S[j - 1]) { unsigned tmp = S[j]; S[j] = S[j - 1]; S[j - 1] = tmp; }
    }
}

// ---------------- kernel 1: swizzled-stream MFMA GEMM + packed top-2/4 ----------------
// Block = 32 px; 4 waves = 4 code-quarters (256 codes each). B loads fully
// contiguous (lane*16B). 4 independent MFMA chains (2 row-tiles x 2 K-halves).
// __launch_bounds__(256,2): round-4-proven allocation (~100-130 VGPR, no spill).
// (256,3) in round 5 forced a 64-VGPR fit -> 504 MB scratch spill, 215 us.
__global__ __launch_bounds__(256, 2) void gemm_swz(
        const float* __restrict__ x, const _Float16* __restrict__ cbs,
        const float* __restrict__ c2p, float* __restrict__ out_idx,
        int* __restrict__ idxbuf, int* __restrict__ cnt,
        int* __restrict__ flagPx, floatx4* __restrict__ flagTop) {
    __shared__ uint2 scr[32][65];   // [px][64 partials + pad] packed (m1,m2)

    const int t = threadIdx.x;
    const int w = t >> 6;        // wave = code quarter
    const int l = t & 63;
    const int l15 = l & 15;
    const int q = l >> 4;
    const int px0 = blockIdx.x * 32;
    const int bimg = px0 >> 10;
    const int hwb = px0 & 1023;
    const float* xb = x + (size_t)bimg * (D_DIM * HW) + hwb;

    // ---- A frags: 32 px x 256 d; A[m=l15][k=q*8+j], px = r*16+l15, d = s*32+q*8+j
    half8 A[2][8];
#pragma unroll
    for (int r = 0; r < 2; ++r)
#pragma unroll
        for (int s = 0; s < 8; ++s) {
            float tmp[8];
#pragma unroll
            for (int j = 0; j < 8; ++j)
                tmp[j] = xb[(size_t)(s * 32 + q * 8 + j) * HW + r * 16 + l15];
            half8 h;
#pragma unroll
            for (int j = 0; j < 8; ++j) h[j] = (_Float16)tmp[j];
            A[r][s] = h;
        }

    // ---- stream this quarter's codes from the fragment-ordered buffer ----
    const _Float16* base = cbs + (size_t)w * 65536;   // quarter: 16*8*64*8 halves
    half8 B[2][8];
#pragma unroll
    for (int s = 0; s < 8; ++s)
        B[0][s] = *(const half8*)(base + (size_t)s * 512 + l * 8);
    float c2c = c2p[w * 256 + l15];

    unsigned m1[2][4], m2[2][4];
#pragma unroll
    for (int r = 0; r < 2; ++r)
#pragma unroll
        for (int a = 0; a < 4; ++a) { m1[r][a] = 0xFFFFFFFFu; m2[r][a] = 0xFFFFFFFFu; }

#pragma unroll 2
    for (int ch = 0; ch < 16; ++ch) {
        const int cur = ch & 1, nxt = cur ^ 1;
        float c2n = 0.f;
        if (ch < 15) {
            const _Float16* nb = base + (size_t)(ch + 1) * 4096;   // 8*512 halves
#pragma unroll
            for (int s = 0; s < 8; ++s)
                B[nxt][s] = *(const half8*)(nb + (size_t)s * 512 + l * 8);
            c2n = c2p[w * 256 + (ch + 1) * 16 + l15];
        }
        // 4 independent MFMA chains: 2 row-tiles x 2 K-halves (chains of 4)
        floatx4 ac[2][2];
#pragma unroll
        for (int r = 0; r < 2; ++r)
#pragma unroll
            for (int h = 0; h < 2; ++h) ac[r][h] = floatx4{0.f, 0.f, 0.f, 0.f};
#pragma unroll
        for (int s = 0; s < 4; ++s) {
            ac[0][0] = __builtin_amdgcn_mfma_f32_16x16x32_f16(A[0][s],     B[cur][s],     ac[0][0], 0, 0, 0);
            ac[1][0] = __builtin_amdgcn_mfma_f32_16x16x32_f16(A[1][s],     B[cur][s],     ac[1][0], 0, 0, 0);
            ac[0][1] = __builtin_amdgcn_mfma_f32_16x16x32_f16(A[0][s + 4], B[cur][s + 4], ac[0][1], 0, 0, 0);
            ac[1][1] = __builtin_amdgcn_mfma_f32_16x16x32_f16(A[1][s + 4], B[cur][s + 4], ac[1][1], 0, 0, 0);
        }
        const unsigned code = (unsigned)(w * 256 + ch * 16 + l15);
#pragma unroll
        for (int r = 0; r < 2; ++r)
#pragma unroll
            for (int a = 0; a < 4; ++a) {
                float dot = ac[r][0][a] + ac[r][1][a];
                // biased score (1+c2) - 2*dot; cb scaled 2^10 -> coeff 2^-9
                float sb = fmaf(-0.001953125f, dot, c2c);
                unsigned p = (__float_as_uint(sb) & 0xFFFFFC00u) | code;
                m2[r][a] = min(m2[r][a], max(m1[r][a], p));
                m1[r][a] = min(m1[r][a], p);
            }
        c2c = c2n;
    }

    // ---- merge 64 packed partial top-2s per pixel ----
#pragma unroll
    for (int r = 0; r < 2; ++r)
#pragma unroll
        for (int a = 0; a < 4; ++a) {
            int px = r * 16 + q * 4 + a;          // D row = q*4+reg
            scr[px][w * 16 + l15] = uint2{m1[r][a], m2[r][a]};
        }
    __syncthreads();
    if (t < 32) {
        unsigned S[4] = {0xFFFFFFFFu, 0xFFFFFFFFu, 0xFFFFFFFFu, 0xFFFFFFFFu};
        for (int p = 0; p < 64; ++p) {
            uint2 e = scr[t][p];
            ins4p(e.x, S);
            ins4p(e.y, S);
        }
        int P = px0 + t;
        int best = (int)(S[0] & 1023u);
        idxbuf[P] = best;
        out_idx[P] = (float)best;
        float cs0 = __uint_as_float(S[0] & 0xFFFFFC00u);
        float cs1 = __uint_as_float(S[1] & 0xFFFFFC00u);
        if (cs1 - cs0 <= MARGIN) {
            int pos = atomicAdd(cnt, 1);
            if (pos < FLAG_CAP) {
                float cs2 = __uint_as_float(S[2] & 0xFFFFFC00u);
                float cs3 = __uint_as_float(S[3] & 0xFFFFFC00u);
                flagPx[pos] = P;
                flagTop[2 * pos]     = floatx4{cs0, (float)(S[0] & 1023u), cs1, (float)(S[1] & 1023u)};
                flagTop[2 * pos + 1] = floatx4{cs2, (float)(S[2] & 1023u), cs3, (float)(S[3] & 1023u)};
            }
        }
    }
}

// ---------------- kernel 2: wave-per-flagged-pixel reference-fp32 emulation --------
// ref (numpy fp32): d2_k = fl(fl(x2 - fl(2*mm_k)) + c2_k); argmin, first-index ties.
__global__ __launch_bounds__(256) void rescore_wave(
        const float* __restrict__ x, const float* __restrict__ cb,
        const float* __restrict__ c2, const int* __restrict__ cnt,
        const int* __restrict__ flagPx, const floatx4* __restrict__ flagTop,
        float* __restrict__ out_idx, int* __restrict__ idxbuf) {
    const int wglobal = blockIdx.x * 4 + (threadIdx.x >> 6);
    const int l = threadIdx.x & 63;
    int n = *cnt; if (n > FLAG_CAP) n = FLAG_CAP;
    for (int i = wglobal; i < n; i += 1024) {
        int P = flagPx[i];
        floatx4 ta = flagTop[2 * i], tb = flagTop[2 * i + 1];
        float s1 = ta[0];
        float cs[4] = {ta[0], ta[2], tb[0], tb[2]};
        int   ck[4] = {(int)ta[1], (int)ta[3], (int)tb[1], (int)tb[3]};
        int nc = 1;
        while (nc < 4 && cs[nc] - s1 <= MARGIN) ++nc;

        const float* xcol = x + (size_t)(P >> 10) * D_DIM * HW + (P & 1023);

        // x2 with numpy's exact pairwise order: lanes 0..15 run the 8-acc chains
        float rj = 0.f;
        if (l < 16) {
            int h = l >> 3, j = l & 7;
            const float* p = xcol + (size_t)(h * 128) * HW;
            float v0 = p[(size_t)j * HW];
            rj = __fmul_rn(v0, v0);
            for (int ii = 1; ii < 16; ++ii) {
                float v = p[(size_t)(ii * 8 + j) * HW];
                rj = __fadd_rn(rj, __fmul_rn(v, v));
            }
        }
        float r0 = __shfl(rj, 0), r1 = __shfl(rj, 1), r2 = __shfl(rj, 2), r3 = __shfl(rj, 3);
        float r4 = __shfl(rj, 4), r5 = __shfl(rj, 5), r6 = __shfl(rj, 6), r7 = __shfl(rj, 7);
        float h0 = __fadd_rn(__fadd_rn(__fadd_rn(r0, r1), __fadd_rn(r2, r3)),
                             __fadd_rn(__fadd_rn(r4, r5), __fadd_rn(r6, r7)));
        r0 = __shfl(rj, 8); r1 = __shfl(rj, 9); r2 = __shfl(rj, 10); r3 = __shfl(rj, 11);
        r4 = __shfl(rj, 12); r5 = __shfl(rj, 13); r6 = __shfl(rj, 14); r7 = __shfl(rj, 15);
        float h1 = __fadd_rn(__fadd_rn(__fadd_rn(r0, r1), __fadd_rn(r2, r3)),
                             __fadd_rn(__fadd_rn(r4, r5), __fadd_rn(r6, r7)));
        float x2 = __fadd_rn(h0, h1);

        // f64 dots (stand-in for faithful sgemm): lane covers d = l, l+64, l+128, l+192
        float xv[4];
#pragma unroll
        for (int u = 0; u < 4; ++u) xv[u] = xcol[(size_t)(l + u * 64) * HW];
        double accd[4] = {0.0, 0.0, 0.0, 0.0};
        for (int jc = 0; jc < nc; ++jc) {
            const float* cr = cb + (size_t)ck[jc] * D_DIM;
            double a = 0.0;
#pragma unroll
            for (int u = 0; u < 4; ++u) a += (double)xv[u] * (double)cr[l + u * 64];
#pragma unroll
            for (int off = 32; off > 0; off >>= 1) a += __shfl_down(a, off);
            accd[jc] = a;
        }
        if (l == 0) {
            float bd = INFINITY; int bi = 0x7fffffff;
            for (int jc = 0; jc < nc; ++jc) {
                float mm = (float)accd[jc];
                float t1 = __fsub_rn(x2, __fmul_rn(2.0f, mm));
                float Dq = __fadd_rn(t1, c2[ck[jc]]);
                if (Dq < bd || (Dq == bd && ck[jc] < bi)) { bd = Dq; bi = ck[jc]; }
            }
            idxbuf[P] = bi;
            out_idx[P] = (float)bi;
        }
    }
}

// ---------------- kernel 3: quantized write + loss partials ----------------
// Block = 64 px x 4 d-groups (256 thr). 512 blocks -> 131072 threads.
__global__ __launch_bounds__(256) void quantize_loss_kernel(
        const float* __restrict__ x, const float* __restrict__ cb,
        const int* __restrict__ idxbuf, float* __restrict__ out_q,
        double* __restrict__ partials) {
    const int t = threadIdx.x;
    const int pxl = t & 63;
    const int dg = t >> 6;           // d-group: 64 d each
    const int P = blockIdx.x * 64 + pxl;
    const int bimg = P >> 10, hw = P & 1023;
    const float* xb = x + (size_t)bimg * D_DIM * HW + hw;
    float* qb = out_q + (size_t)bimg * D_DIM * HW + hw;
    const floatx4* crow = (const floatx4*)(cb + (size_t)idxbuf[P] * D_DIM) + dg * 16;
    float lsum = 0.f;
#pragma unroll 4
    for (int i = 0; i < 16; ++i) {
        floatx4 cv = crow[i];
        int dbase = dg * 64 + i * 4;
#pragma unroll
        for (int j = 0; j < 4; ++j) {
            size_t off = (size_t)(dbase + j) * HW;
            float xv = xb[off];
            qb[off] = cv[j];                 // coalesced across pxl lanes
            float df = cv[j] - xv;
            lsum = fmaf(df, df, lsum);
        }
    }
    double ds = (double)lsum;
#pragma unroll
    for (int off = 32; off > 0; off >>= 1) ds += __shfl_down(ds, off);
    __shared__ double sred[4];
    if ((t & 63) == 0) sred[t >> 6] = ds;
    __syncthreads();
    if (t == 0) partials[blockIdx.x] = sred[0] + sred[1] + sred[2] + sred[3];
}

// ---------------- kernel 4: loss scalars ----------------
__global__ __launch_bounds__(64) void finalize_loss(const double* __restrict__ partials,
                                                    float* __restrict__ out) {
    double s = 0.0;
    for (int i = threadIdx.x; i < 512; i += 64) s += partials[i];
#pragma unroll
    for (int off = 32; off > 0; off >>= 1) s += __shfl_down(s, off);
    if (threadIdx.x == 0) {
        double m = s / (double)NELEM;
        out[OFF_QLOSS] = (float)m;
        out[OFF_ELOSS] = (float)m;            // numerically identical to q_loss
        out[OFF_VQ]    = (float)(1.25 * m);   // q + 0.25*e
    }
}

extern "C" void kernel_launch(void* const* d_in, const int* in_sizes, int n_in,
                              void* d_out, int out_size, void* d_ws, size_t ws_size,
                              hipStream_t stream) {
    const float* x  = (const float*)d_in[0];   // (32,256,32,32)
    const float* cb = (const float*)d_in[1];   // (1024,256)
    float* out = (float*)d_out;
    char* ws = (char*)d_ws;

    int*      idxbuf  = (int*)(ws + WS_IDX);
    float*    c2      = (float*)(ws + WS_C2);
    float*    c2p     = (float*)(ws + WS_C2P);
    int*      cnt     = (int*)(ws + WS_CNT);
    double*   partials= (double*)(ws + WS_PART);
    int*      flagPx  = (int*)(ws + WS_FLAGPX);
    floatx4*  flagTop = (floatx4*)(ws + WS_FLAGTOP);
    _Float16* cbs     = (_Float16*)(ws + WS_CBS);

    prep_kernel<<<260, 256, 0, stream>>>(cb, cbs, c2, c2p, cnt);
    gemm_swz<<<NPIX / 32, 256, 0, stream>>>(x, cbs, c2p, out + OFF_IDX, idxbuf,
                                            cnt, flagPx, flagTop);
    rescore_wave<<<256, 256, 0, stream>>>(x, cb, c2, cnt, flagPx, flagTop,
                                          out + OFF_IDX, idxbuf);
    quantize_loss_kernel<<<NPIX / 64, 256, 0, stream>>>(x, cb, idxbuf, out, partials);
    finalize_loss<<<1, 64, 0, stream>>>(partials, out);
}

// Round 7
// 152.881 us; speedup vs baseline: 2.0213x; 1.9242x over previous
//
#include <hip/hip_runtime.h>
#include <cstdint>

typedef float floatx4 __attribute__((ext_vector_type(4)));
typedef _Float16 half8 __attribute__((ext_vector_type(8)));
typedef _Float16 half4v __attribute__((ext_vector_type(4)));

#define D_DIM 256
#define HW 1024
#define K_CODES 1024
#define NPIX 32768          // B*H*W
#define NELEM 8388608       // B*D*H*W

// output layout (floats): [quantized 8388608][q_loss][e_loss][vq_loss][idx 32768]
#define OFF_QLOSS 8388608
#define OFF_ELOSS 8388609
#define OFF_VQ    8388610
#define OFF_IDX   8388611

// ws layout (bytes) — total ~0.94 MB
#define WS_IDX     0         // int * 32768 = 131072
#define WS_C2      131072    // float * 1024 = 4096
#define WS_CNT     135168    // int (+pad) = 64
#define WS_PART    135232    // double * 1024 = 8192
#define WS_FLAGPX  143424    // int * 8192 = 32768
#define WS_FLAGTOP 176192    // floatx4 * 2 * 8192 = 262144
#define WS_CBS     438336    // swizzled fp16 codebook = 524288
#define FLAG_CAP   8192

// ref fp32 window 6.1e-5 + fp16 GEMM err ~6e-5, with slack (round-4-proven value)
#define MARGIN 2.5e-4f

// ---- numpy pairwise sum emulation for sum(v*v) over 256 elements ----
__device__ __forceinline__ float np_pairwise_sq_256(const float* __restrict__ a, int stride) {
    float half[2];
#pragma unroll
    for (int h = 0; h < 2; ++h) {
        const float* p = a + (size_t)(h * 128) * stride;
        float r[8];
#pragma unroll
        for (int j = 0; j < 8; ++j) { float t = p[(size_t)j * stride]; r[j] = __fmul_rn(t, t); }
        for (int i = 8; i < 128; i += 8)
#pragma unroll
            for (int j = 0; j < 8; ++j) {
                float t = p[(size_t)(i + j) * stride];
                r[j] = __fadd_rn(r[j], __fmul_rn(t, t));
            }
        half[h] = __fadd_rn(__fadd_rn(__fadd_rn(r[0], r[1]), __fadd_rn(r[2], r[3])),
                            __fadd_rn(__fadd_rn(r[4], r[5]), __fadd_rn(r[6], r[7])));
    }
    return __fadd_rn(half[0], half[1]);
}

// ---------------- kernel 0: prep ----------------
// blocks 0..255: swizzle codebook into MFMA-fragment order (scaled x1024):
//   code c: half=c>>9, ch=(c>>4)&31, l15=c&15; d: s=d>>5, q=(d>>3)&3, j=d&7
//   offset = (((half*32 + ch)*8 + s)*64 + (q*16+l15))*8 + j   (halves)
// -> a wave's B-frag load for (ch,s) is one contiguous 1 KB block (lane*16B).
// blocks 256..259: c2 (numpy-pairwise exact); b==256,t==0 zeroes cnt.
__global__ __launch_bounds__(256) void prep_kernel(const float* __restrict__ cb,
                                                   _Float16* __restrict__ cbs,
                                                   float* __restrict__ c2,
                                                   int* __restrict__ cnt) {
    int b = blockIdx.x;
    if (b < 256) {
        int idx = b * 256 + threadIdx.x;   // (code, d-quad)
        int c = idx >> 6;
        int d = (idx & 63) * 4;
        int s = d >> 5, q = (d >> 3) & 3, j0 = d & 7;
        int half = c >> 9, ch = (c >> 4) & 31, l15 = c & 15;
        int lane = q * 16 + l15;
        size_t o = ((((size_t)(half * 32 + ch) * 8 + s) * 64 + lane) * 8 + j0);
        floatx4 v = *(const floatx4*)(cb + (size_t)c * D_DIM + d);
        half4v h;
#pragma unroll
        for (int j = 0; j < 4; ++j) h[j] = (_Float16)(v[j] * 1024.0f);  // exact pow2
        *(half4v*)(cbs + o) = h;
    } else {
        if (b == 256 && threadIdx.x == 0) *cnt = 0;
        int k = (b - 256) * 256 + threadIdx.x;
        c2[k] = np_pairwise_sq_256(cb + (size_t)k * D_DIM, 1);
    }
}

// top-4 insert, no index tiebreak (ties land in MARGIN, resolved by rescore)
__device__ __forceinline__ void ins4v(float v, int k, float* S, int* I) {
    if (v < S[3]) {
        S[3] = v; I[3] = k;
#pragma unroll
        for (int j = 3; j > 0; --j) {
            if (S[j] < S[j - 1]) {
                float ts = S[j]; S[j] = S[j - 1]; S[j - 1] = ts;
                int   ti = I[j]; I[j] = I[j - 1]; I[j - 1] = ti;
            }
        }
    }
}

// ---------------- kernel 1: MFMA stream GEMM (round-4 structure, swizzled B) -------
// ROUND-4-VERBATIM register structure: wave = 32 px x 512 codes, 32 chunks of 16,
// A[2][8] via tmp[64], B[2][8] double-buffered, unpacked float/int top-2 state,
// float scr[4][32*65], #pragma unroll 4, __launch_bounds__(256,2).
// That shape compiled to VGPR=100 / WRITE_SIZE=346KB (NO spill) in round 4.
// ONLY delta: B loads now read the fragment-ordered cbs -> fully contiguous
// 1 KB per instruction (round 4's were 16-segment scatters; rounds 5/6's
// restructured loop spilled 498 MB to scratch — structure reverted, swizzle kept).
__global__ __launch_bounds__(256, 2) void gemm_swz(
        const float* __restrict__ x, const _Float16* __restrict__ cbs,
        const float* __restrict__ c2, float* __restrict__ out_idx,
        int* __restrict__ idxbuf, int* __restrict__ cnt,
        int* __restrict__ flagPx, floatx4* __restrict__ flagTop) {
    __shared__ float scr[4][32 * 65];   // SoA [m1|i1|m2|i2][part][px pad65] = 33 KB

    const int t = threadIdx.x;
    const int w = t >> 6;
    const int l = t & 63;
    const int l15 = l & 15;
    const int q = l >> 4;
    const int pxg = w >> 1;          // pixel group 0/1 (32 px each)
    const int half = w & 1;          // code half 0/1 (512 codes each)
    const int px0 = blockIdx.x * 64;
    const int bimg = px0 >> 10;      // 64-px blocks never straddle images
    const int hwb = (px0 & 1023) + pxg * 32;
    const float* xb = x + (size_t)bimg * (D_DIM * HW);

    // ---- load A: 32 px x 256 d from fp32 NCHW, convert to f16 frags in regs ----
    // A[m=l15][k=q*8+j] per 16x16x32 layout; d = s*32 + q*8 + j
    half8 A[2][8];
#pragma unroll
    for (int r = 0; r < 2; ++r) {
        float tmp[64];
#pragma unroll
        for (int s = 0; s < 8; ++s)
#pragma unroll
            for (int j = 0; j < 8; ++j)
                tmp[s * 8 + j] = xb[(size_t)(s * 32 + q * 8 + j) * HW + hwb + r * 16 + l15];
#pragma unroll
        for (int s = 0; s < 8; ++s) {
            half8 h;
#pragma unroll
            for (int j = 0; j < 8; ++j) h[j] = (_Float16)tmp[s * 8 + j];
            A[r][s] = h;
        }
    }

    // ---- stream codes from fragment-ordered buffer: contiguous lane*16B loads ----
    const _Float16* base = cbs + (size_t)half * 131072;   // half block: 32*8*64*8 halves
    half8 B[2][8];
#pragma unroll
    for (int s = 0; s < 8; ++s)
        B[0][s] = *(const half8*)(base + (size_t)s * 512 + l * 8);
    float c2cur = c2[half * 512 + l15];

    float m1[2][4], m2[2][4]; int i1[2][4], i2[2][4];
#pragma unroll
    for (int r = 0; r < 2; ++r)
#pragma unroll
        for (int a = 0; a < 4; ++a) {
            m1[r][a] = INFINITY; m2[r][a] = INFINITY; i1[r][a] = 0; i2[r][a] = 0;
        }

#pragma unroll 4
    for (int ch = 0; ch < 32; ++ch) {
        const int cur = ch & 1, nxt = cur ^ 1;
        float c2n = 0.f;
        if (ch < 31) {   // prefetch next chunk while computing this one
            const _Float16* nb = base + (size_t)(ch + 1) * 4096;   // 8*512 halves
#pragma unroll
            for (int s = 0; s < 8; ++s)
                B[nxt][s] = *(const half8*)(nb + (size_t)s * 512 + l * 8);
            c2n = c2[half * 512 + (ch + 1) * 16 + l15];
        }
        // 4 independent MFMA chains (2 row-tiles x 2 K-halves)
        floatx4 ac[2][2];
#pragma unroll
        for (int r = 0; r < 2; ++r)
#pragma unroll
            for (int h = 0; h < 2; ++h) ac[r][h] = floatx4{0.f, 0.f, 0.f, 0.f};
#pragma unroll
        for (int s = 0; s < 4; ++s) {
            ac[0][0] = __builtin_amdgcn_mfma_f32_16x16x32_f16(A[0][s],     B[cur][s],     ac[0][0], 0, 0, 0);
            ac[1][0] = __builtin_amdgcn_mfma_f32_16x16x32_f16(A[1][s],     B[cur][s],     ac[1][0], 0, 0, 0);
            ac[0][1] = __builtin_amdgcn_mfma_f32_16x16x32_f16(A[0][s + 4], B[cur][s + 4], ac[0][1], 0, 0, 0);
            ac[1][1] = __builtin_amdgcn_mfma_f32_16x16x32_f16(A[1][s + 4], B[cur][s + 4], ac[1][1], 0, 0, 0);
        }
        const int code = half * 512 + ch * 16 + l15;
#pragma unroll
        for (int r = 0; r < 2; ++r)
#pragma unroll
            for (int a = 0; a < 4; ++a) {
                float dot = ac[r][0][a] + ac[r][1][a];
                float s = fmaf(-0.001953125f, dot, c2cur);   // c2 - 2*dot (cb scaled 2^10)
                if (s < m1[r][a]) { m2[r][a] = m1[r][a]; i2[r][a] = i1[r][a]; m1[r][a] = s; i1[r][a] = code; }
                else if (s < m2[r][a]) { m2[r][a] = s; i2[r][a] = code; }
            }
        c2cur = c2n;
    }

    // ---- merge 32 partial top-2s per px (the only barrier in the kernel) ----
    const int part = half * 16 + l15;
#pragma unroll
    for (int r = 0; r < 2; ++r)
#pragma unroll
        for (int a = 0; a < 4; ++a) {
            int px = pxg * 32 + r * 16 + q * 4 + a;
            int o = part * 65 + px;
            scr[0][o] = m1[r][a];
            scr[1][o] = __int_as_float(i1[r][a]);
            scr[2][o] = m2[r][a];
            scr[3][o] = __int_as_float(i2[r][a]);
        }
    __syncthreads();
    if (t < 64) {
        float S[4] = {INFINITY, INFINITY, INFINITY, INFINITY};
        int   I[4] = {0x7fffffff, 0x7fffffff, 0x7fffffff, 0x7fffffff};
        for (int p = 0; p < 32; ++p) {   // reads: stride 65 -> conflict-free
            int o = p * 65 + t;
            ins4v(scr[0][o], __float_as_int(scr[1][o]), S, I);
            ins4v(scr[2][o], __float_as_int(scr[3][o]), S, I);
        }
        int P = px0 + t;
        idxbuf[P] = I[0];
        out_idx[P] = (float)I[0];
        if (S[1] - S[0] <= MARGIN) {     // near-tie: queue for exact reference emulation
            int pos = atomicAdd(cnt, 1);
            if (pos < FLAG_CAP) {
                flagPx[pos] = P;
                flagTop[2 * pos]     = floatx4{S[0], (float)I[0], S[1], (float)I[1]};
                flagTop[2 * pos + 1] = floatx4{S[2], (float)I[2], S[3], (float)I[3]};
            }
        }
    }
}

// ---------------- kernel 2: wave-per-flagged-pixel reference-fp32 emulation --------
// ref (numpy fp32): d2_k = fl(fl(x2 - fl(2*mm_k)) + c2_k); argmin, first-index ties.
__global__ __launch_bounds__(256) void rescore_wave(
        const float* __restrict__ x, const float* __restrict__ cb,
        const float* __restrict__ c2, const int* __restrict__ cnt,
        const int* __restrict__ flagPx, const floatx4* __restrict__ flagTop,
        float* __restrict__ out_idx, int* __restrict__ idxbuf) {
    const int wglobal = blockIdx.x * 4 + (threadIdx.x >> 6);
    const int l = threadIdx.x & 63;
    int n = *cnt; if (n > FLAG_CAP) n = FLAG_CAP;
    for (int i = wglobal; i < n; i += 1024) {
        int P = flagPx[i];
        floatx4 ta = flagTop[2 * i], tb = flagTop[2 * i + 1];
        float s1 = ta[0];
        float cs[4] = {ta[0], ta[2], tb[0], tb[2]};
        int   ck[4] = {(int)ta[1], (int)ta[3], (int)tb[1], (int)tb[3]};
        int nc = 1;
        while (nc < 4 && cs[nc] - s1 <= MARGIN) ++nc;

        const float* xcol = x + (size_t)(P >> 10) * D_DIM * HW + (P & 1023);

        // x2 with numpy's exact pairwise order: lanes 0..15 run the 8-acc chains
        float rj = 0.f;
        if (l < 16) {
            int h = l >> 3, j = l & 7;
            const float* p = xcol + (size_t)(h * 128) * HW;
            float v0 = p[(size_t)j * HW];
            rj = __fmul_rn(v0, v0);
            for (int ii = 1; ii < 16; ++ii) {
                float v = p[(size_t)(ii * 8 + j) * HW];
                rj = __fadd_rn(rj, __fmul_rn(v, v));
            }
        }
        float r0 = __shfl(rj, 0), r1 = __shfl(rj, 1), r2 = __shfl(rj, 2), r3 = __shfl(rj, 3);
        float r4 = __shfl(rj, 4), r5 = __shfl(rj, 5), r6 = __shfl(rj, 6), r7 = __shfl(rj, 7);
        float h0 = __fadd_rn(__fadd_rn(__fadd_rn(r0, r1), __fadd_rn(r2, r3)),
                             __fadd_rn(__fadd_rn(r4, r5), __fadd_rn(r6, r7)));
        r0 = __shfl(rj, 8); r1 = __shfl(rj, 9); r2 = __shfl(rj, 10); r3 = __shfl(rj, 11);
        r4 = __shfl(rj, 12); r5 = __shfl(rj, 13); r6 = __shfl(rj, 14); r7 = __shfl(rj, 15);
        float h1 = __fadd_rn(__fadd_rn(__fadd_rn(r0, r1), __fadd_rn(r2, r3)),
                             __fadd_rn(__fadd_rn(r4, r5), __fadd_rn(r6, r7)));
        float x2 = __fadd_rn(h0, h1);

        // f64 dots (stand-in for faithful sgemm): lane covers d = l, l+64, l+128, l+192
        float xv[4];
#pragma unroll
        for (int u = 0; u < 4; ++u) xv[u] = xcol[(size_t)(l + u * 64) * HW];
        double accd[4] = {0.0, 0.0, 0.0, 0.0};
        for (int jc = 0; jc < nc; ++jc) {
            const float* cr = cb + (size_t)ck[jc] * D_DIM;
            double a = 0.0;
#pragma unroll
            for (int u = 0; u < 4; ++u) a += (double)xv[u] * (double)cr[l + u * 64];
#pragma unroll
            for (int off = 32; off > 0; off >>= 1) a += __shfl_down(a, off);
            accd[jc] = a;
        }
        if (l == 0) {
            float bd = INFINITY; int bi = 0x7fffffff;
            for (int jc = 0; jc < nc; ++jc) {
                float mm = (float)accd[jc];
                float t1 = __fsub_rn(x2, __fmul_rn(2.0f, mm));
                float Dq = __fadd_rn(t1, c2[ck[jc]]);
                if (Dq < bd || (Dq == bd && ck[jc] < bi)) { bd = Dq; bi = ck[jc]; }
            }
            idxbuf[P] = bi;
            out_idx[P] = (float)bi;
        }
    }
}

// ---------------- kernel 3: quantized write + loss partials ----------------
// Block = 32 px x 8 d-groups (256 thr); 1024 blocks for latency hiding.
__global__ __launch_bounds__(256) void quantize_loss_kernel(
        const float* __restrict__ x, const float* __restrict__ cb,
        const int* __restrict__ idxbuf, float* __restrict__ out_q,
        double* __restrict__ partials) {
    const int t = threadIdx.x;
    const int pxl = t & 31;
    const int dg = t >> 5;           // d-group: 32 d each
    const int P = blockIdx.x * 32 + pxl;
    const int bimg = P >> 10, hw = P & 1023;
    const float* xb = x + (size_t)bimg * D_DIM * HW + hw;
    float* qb = out_q + (size_t)bimg * D_DIM * HW + hw;
    const floatx4* crow = (const floatx4*)(cb + (size_t)idxbuf[P] * D_DIM) + dg * 8;
    float lsum = 0.f;
#pragma unroll
    for (int i = 0; i < 8; ++i) {
        floatx4 cv = crow[i];
        int dbase = dg * 32 + i * 4;
#pragma unroll
        for (int j = 0; j < 4; ++j) {
            size_t off = (size_t)(dbase + j) * HW;
            float xv = xb[off];
            qb[off] = cv[j];                 // coalesced across pxl lanes
            float df = cv[j] - xv;
            lsum = fmaf(df, df, lsum);
        }
    }
    double ds = (double)lsum;
#pragma unroll
    for (int off = 32; off > 0; off >>= 1) ds += __shfl_down(ds, off);
    __shared__ double sred[4];
    if ((t & 63) == 0) sred[t >> 6] = ds;
    __syncthreads();
    if (t == 0) partials[blockIdx.x] = sred[0] + sred[1] + sred[2] + sred[3];
}

// ---------------- kernel 4: loss scalars ----------------
__global__ __launch_bounds__(64) void finalize_loss(const double* __restrict__ partials,
                                                    float* __restrict__ out) {
    double s = 0.0;
    for (int i = threadIdx.x; i < 1024; i += 64) s += partials[i];
#pragma unroll
    for (int off = 32; off > 0; off >>= 1) s += __shfl_down(s, off);
    if (threadIdx.x == 0) {
        double m = s / (double)NELEM;
        out[OFF_QLOSS] = (float)m;
        out[OFF_ELOSS] = (float)m;            // numerically identical to q_loss
        out[OFF_VQ]    = (float)(1.25 * m);   // q + 0.25*e
    }
}

extern "C" void kernel_launch(void* const* d_in, const int* in_sizes, int n_in,
                              void* d_out, int out_size, void* d_ws, size_t ws_size,
                              hipStream_t stream) {
    const float* x  = (const float*)d_in[0];   // (32,256,32,32)
    const float* cb = (const float*)d_in[1];   // (1024,256)
    float* out = (float*)d_out;
    char* ws = (char*)d_ws;

    int*      idxbuf  = (int*)(ws + WS_IDX);
    float*    c2      = (float*)(ws + WS_C2);
    int*      cnt     = (int*)(ws + WS_CNT);
    double*   partials= (double*)(ws + WS_PART);
    int*      flagPx  = (int*)(ws + WS_FLAGPX);
    floatx4*  flagTop = (floatx4*)(ws + WS_FLAGTOP);
    _Float16* cbs     = (_Float16*)(ws + WS_CBS);

    prep_kernel<<<260, 256, 0, stream>>>(cb, cbs, c2, cnt);
    gemm_swz<<<NPIX / 64, 256, 0, stream>>>(x, cbs, c2, out + OFF_IDX, idxbuf,
                                            cnt, flagPx, flagTop);
    rescore_wave<<<256, 256, 0, stream>>>(x, cb, c2, cnt, flagPx, flagTop,
                                          out + OFF_IDX, idxbuf);
    quantize_loss_kernel<<<NPIX / 32, 256, 0, stream>>>(x, cb, idxbuf, out, partials);
    finalize_loss<<<1, 64, 0, stream>>>(partials, out);
}